// Round 12
// baseline (287.508 us; speedup 1.0000x reference)
//
#include <hip/hip_runtime.h>

// Swin window attention, fully fused, persistent blocks (1 block/CU, 256
// blocks, 16-batch loop per block).
//
// R10 = R9 (126.4us; swapped-QK^T in-lane softmax) + LDS-issue-bandwidth cuts.
// R9 counters: MfmaUtil 13.7, VALUBusy 21, HBM 20% -- none saturated; per-CU
// ds-op census shows ~5.4us/iter of LDS issue (7.9us/iter total): ph1 re-reads
// xs A-frags per n-task (24 b128/wave) + 16-24 scalar u16 q/k stores; ph2/ph5
// store D-frags as 8 scalar ops each. Fixes (structure byte-identical to R9):
//  1. Hoist xs A-frags: each wave's 3 ph1 tasks share mh=wave&1 -> load the
//     2 m-tiles x 4 k-slices ONCE into regs (8 b128, 32 VGPR), reuse x3.
//  2. Swap QKV-GEMM operands for q/k tasks -- mfma(W,X) puts the channel in
//     D's m-index, so acc[0..3] are contiguous channels -> ushort4 stores
//     (v task stays unswapped: its [ch][tok] layout already vectorizes).
//  3. Same swap for PV (oa: 8 u16 -> 2 ushort4) and out-proj (osr: 8 scalar
//     f32 -> 2 float4; bias as one float4 from b_out).
// R6/R7/R8 lessons honored: no role-split, no f32 payload across barriers,
// no register-staging of cross-wave-shared data.
//
// MFMA 16x16x32 bf16 fragment layouts (HW-verified per guide m89/m91/m120):
//   A[m][k]: m = lane&15, k = (lane>>4)*8 + j   (8 contiguous bf16 = 16B)
//   B[k][n]: n = lane&15, k = (lane>>4)*8 + j
//   D[m][n]: n = lane&15, m = (lane>>4)*4 + reg
// Swapped forms used here: mfma(W-frag, X-frag) -> D[m=chan][n=token];
// mfma(K,Q) -> lane owns a full q-row of S (in-lane softmax, R9).

typedef __bf16 bf16x8 __attribute__((ext_vector_type(8)));
typedef short  s16x8  __attribute__((ext_vector_type(8)));
typedef float  f32x4  __attribute__((ext_vector_type(4)));

static __device__ __forceinline__ unsigned short f2bf(float f) {
  __bf16 h = (__bf16)f;                      // RNE; compiler emits cvt_pk pairs
  return __builtin_bit_cast(unsigned short, h);
}
static __device__ __forceinline__ ushort4 pack4(f32x4 a) {
  ushort4 pk;
  pk.x = f2bf(a[0]); pk.y = f2bf(a[1]); pk.z = f2bf(a[2]); pk.w = f2bf(a[3]);
  return pk;
}
static __device__ __forceinline__ f32x4 mfma16(s16x8 a, s16x8 b, f32x4 c) {
  return __builtin_amdgcn_mfma_f32_16x16x32_bf16(
      __builtin_bit_cast(bf16x8, a), __builtin_bit_cast(bf16x8, b), c, 0, 0, 0);
}
// LDS-only barrier: orders ds ops across waves without draining vmcnt.
static __device__ __forceinline__ void bar_lds() {
  __builtin_amdgcn_sched_barrier(0);
  asm volatile("s_waitcnt lgkmcnt(0)" ::: "memory");
  __builtin_amdgcn_s_barrier();
  __builtin_amdgcn_sched_barrier(0);
}

// ---------------- prep: transpose + bf16-cast weights into workspace --------
__global__ void prep_weights(const float* __restrict__ wqkv,
                             const float* __restrict__ wout,
                             unsigned short* __restrict__ wqkvT,
                             unsigned short* __restrict__ woutT) {
  int idx = blockIdx.x * blockDim.x + threadIdx.x;
  const int total1 = 384 * 128;
  if (idx < total1) {
    int n = idx >> 7, k = idx & 127;
    wqkvT[idx] = f2bf(wqkv[k * 384 + n]);
  } else {
    int i2 = idx - total1;
    int n = i2 >> 7, k = i2 & 127;
    woutT[i2] = f2bf(wout[k * 128 + n]);
  }
}

// ---------------- LDS layout ------------------------------------------------
//   xs   [64][136] bf16   17408  @ 0        (staged x window, batch-cycled)
//   q    [64][136] bf16   17408  @ 17408
//   k    [64][136] bf16   17408  @ 34816
//   v    [128][72] bf16   18432  @ 52224    (v transposed: [ch][tok])
//   S    [4][64][72] bf16 36864  @ 70656    (P in ph2; f32 osr[64][132] union)
//   oa   [64][136] bf16   17408  @ 107520
//   bias [64][68] f32     17408  @ 124928   (pre-scaled by log2e)
#define OFF_XS  0
#define OFF_Q   17408
#define OFF_K   34816
#define OFF_V   52224
#define OFF_S   70656
#define OFF_OA  107520
#define OFF_BI  124928
#define SMEM_SZ 142336

#define BATCH_STRIDE (128 * 128 * 128)   // floats per batch image

__global__ __launch_bounds__(1024, 4)
void swin_fused(const float* __restrict__ x,
                const unsigned short* __restrict__ wqkvT,
                const unsigned short* __restrict__ woutT,
                const float* __restrict__ b_out,
                const float* __restrict__ pe,     // [15][15]
                const float* __restrict__ ulm,    // [64][64]
                const float* __restrict__ lrm,    // [64][64]
                float* __restrict__ out) {
  __shared__ __align__(16) unsigned char smem[SMEM_SZ];
  unsigned short* xs_s   = (unsigned short*)(smem + OFF_XS);
  unsigned short* q_s    = (unsigned short*)(smem + OFF_Q);
  unsigned short* k_s    = (unsigned short*)(smem + OFF_K);
  unsigned short* v_s    = (unsigned short*)(smem + OFF_V);
  unsigned short* S_s    = (unsigned short*)(smem + OFF_S);
  float*          osr_s  = (float*)(smem + OFF_S);          // union with S
  unsigned short* oa_s   = (unsigned short*)(smem + OFF_OA);
  float*          bias_s = (float*)(smem + OFF_BI);

  const int tid  = threadIdx.x;
  const int lane = tid & 63;
  const int wave = tid >> 6;       // 0..15
  const int ln15 = lane & 15;
  const int quad = lane >> 4;
  const int m_sub = quad << 2;

  const int wh = blockIdx.x >> 4, ww = blockIdx.x & 15;

  // per-thread x/out addresses: 2 token-quarter-rows per thread, constant
  // across batches (only the batch base advances).
  const int tokA = tid >> 5, c4 = tid & 31;    // 32 float4 per 128-ch token row
  const int tokB = tokA + 32;
  const int giA = ((wh << 3) + (tokA >> 3) + 4) & 127;
  const int gjA = ((ww << 3) + (tokA & 7) + 4) & 127;
  const int giB = ((wh << 3) + (tokB >> 3) + 4) & 127;
  const int gjB = ((ww << 3) + (tokB & 7) + 4) & 127;
  const long offA = (long)(giA * 128 + gjA) * 128 + c4 * 4;
  const long offB = (long)(giB * 128 + gjB) * 128 + c4 * 4;
  const float* xA = x + offA;
  const float* xB = x + offB;

  // ph1 task constants: fixed mh = wave&1; col0 = (wave>>1)*16 for q/k/v.
  const int mh   = wave & 1;
  const int col0 = (wave >> 1) << 4;

  // ---- prologue: stage batch-0 x window + build bias table (once) ----
  {
    float4 a0 = *(const float4*)xA;
    float4 b0 = *(const float4*)xB;
    ushort4 pk;
    pk.x = f2bf(a0.x); pk.y = f2bf(a0.y); pk.z = f2bf(a0.z); pk.w = f2bf(a0.w);
    *(ushort4*)(xs_s + tokA * 136 + c4 * 4) = pk;
    pk.x = f2bf(b0.x); pk.y = f2bf(b0.y); pk.z = f2bf(b0.z); pk.w = f2bf(b0.w);
    *(ushort4*)(xs_s + tokB * 136 + c4 * 4) = pk;

    const bool has_ul = (wh == 15), has_lr = (ww == 15);
    const float log2e = 1.4426950408889634f;
#pragma unroll
    for (int it = 0; it < 4; ++it) {
      int t = tid + it * 1024;             // 4096 bias entries
      int i = t >> 6, j = t & 63;
      int r0 = (j >> 3) - (i >> 3) + 7;
      int r1 = (j & 7) - (i & 7) + 7;
      float bsum = pe[r0 * 15 + r1];
      if (has_ul) bsum += ulm[t];
      if (has_lr) bsum += lrm[t];
      bias_s[i * 68 + j] = bsum * log2e;   // log2 domain for exp2 softmax
    }
  }
  __syncthreads();

  for (int b = 0; b < 16; ++b) {
    // ---- phase 1: QKV GEMM + prefetch issue ------------------------------
    float4 pfA, pfB;
    const bool pf = (b < 15);
    if (pf) {
      pfA = *(const float4*)(xA + (b + 1) * BATCH_STRIDE);
      pfB = *(const float4*)(xB + (b + 1) * BATCH_STRIDE);
    }
    {
      // hoisted A-frags: this wave's 2 m-tiles x 4 k-slices, read ONCE.
      s16x8 afr[2][4];
#pragma unroll
      for (int mi = 0; mi < 2; ++mi)
#pragma unroll
        for (int ks = 0; ks < 4; ++ks)
          afr[mi][ks] = *(const s16x8*)(xs_s + ((mh * 2 + mi) * 16 + ln15) * 136 + ks * 32 + quad * 8);

      // q task (swapped: D[m=chan][n=token] -> ushort4 store per mi)
      {
        const unsigned short* wp = wqkvT + (col0 + ln15) * 128 + quad * 8;
        s16x8 bfr[4];
#pragma unroll
        for (int ks = 0; ks < 4; ++ks) bfr[ks] = *(const s16x8*)(wp + ks * 32);
#pragma unroll
        for (int mi = 0; mi < 2; ++mi) {
          f32x4 acc = {0.f, 0.f, 0.f, 0.f};
#pragma unroll
          for (int ks = 0; ks < 4; ++ks) acc = mfma16(bfr[ks], afr[mi][ks], acc);
          *(ushort4*)(q_s + ((mh * 2 + mi) * 16 + ln15) * 136 + col0 + m_sub) = pack4(acc);
        }
      }
      // k task (swapped)
      {
        const unsigned short* wp = wqkvT + (128 + col0 + ln15) * 128 + quad * 8;
        s16x8 bfr[4];
#pragma unroll
        for (int ks = 0; ks < 4; ++ks) bfr[ks] = *(const s16x8*)(wp + ks * 32);
#pragma unroll
        for (int mi = 0; mi < 2; ++mi) {
          f32x4 acc = {0.f, 0.f, 0.f, 0.f};
#pragma unroll
          for (int ks = 0; ks < 4; ++ks) acc = mfma16(bfr[ks], afr[mi][ks], acc);
          *(ushort4*)(k_s + ((mh * 2 + mi) * 16 + ln15) * 136 + col0 + m_sub) = pack4(acc);
        }
      }
      // v task (unswapped: D[m=tok][n=chan] -> ushort4 over tok, [ch][tok])
      {
        const unsigned short* wp = wqkvT + (256 + col0 + ln15) * 128 + quad * 8;
        s16x8 bfr[4];
#pragma unroll
        for (int ks = 0; ks < 4; ++ks) bfr[ks] = *(const s16x8*)(wp + ks * 32);
#pragma unroll
        for (int mi = 0; mi < 2; ++mi) {
          f32x4 acc = {0.f, 0.f, 0.f, 0.f};
#pragma unroll
          for (int ks = 0; ks < 4; ++ks) acc = mfma16(afr[mi][ks], bfr[ks], acc);
          *(ushort4*)(v_s + (col0 + ln15) * 72 + (mh * 2 + mi) * 16 + m_sub) = pack4(acc);
        }
      }
    }
    bar_lds();

    // ---- phase 2 (fused): swapped QK^T -> in-lane softmax -> P -> PV -----
    {
      const int h  = wave >> 2;
      const int mt = wave & 3;
      unsigned short* Sh = S_s + h * 64 * 72;
      s16x8 qf = *(const s16x8*)(q_s + (mt * 16 + ln15) * 136 + h * 32 + quad * 8);
      const float scale2 = 0.17677669529663687f * 1.4426950408889634f;
      const float* brow = bias_s + (mt * 16 + ln15) * 68;   // bias'[qt][*]
      f32x4 sv[4];
#pragma unroll
      for (int nt = 0; nt < 4; ++nt) {
        s16x8 kf = *(const s16x8*)(k_s + (nt * 16 + ln15) * 136 + h * 32 + quad * 8);
        f32x4 acc = {0.f, 0.f, 0.f, 0.f};
        acc = mfma16(kf, qf, acc);              // swapped: D[kt-local][qt-local]
        float4 bv = *(const float4*)(brow + nt * 16 + quad * 4);
#pragma unroll
        for (int r = 0; r < 4; ++r)
          sv[nt][r] = acc[r] * scale2 + ((const float*)&bv)[r];
      }

      // write next batch's prefetched x window (xs dead since ph1-end bar)
      if (pf) {
        ushort4 pk;
        pk.x = f2bf(pfA.x); pk.y = f2bf(pfA.y); pk.z = f2bf(pfA.z); pk.w = f2bf(pfA.w);
        *(ushort4*)(xs_s + tokA * 136 + c4 * 4) = pk;
        pk.x = f2bf(pfB.x); pk.y = f2bf(pfB.y); pk.z = f2bf(pfB.z); pk.w = f2bf(pfB.w);
        *(ushort4*)(xs_s + tokB * 136 + c4 * 4) = pk;
      }

      // in-lane softmax over the lane's full q-row + 2 cross-quad shfls.
      float mnt[4];
#pragma unroll
      for (int nt = 0; nt < 4; ++nt)
        mnt[nt] = fmaxf(fmaxf(sv[nt][0], sv[nt][1]), fmaxf(sv[nt][2], sv[nt][3]));
      float m0 = fmaxf(fmaxf(mnt[0], mnt[1]), fmaxf(mnt[2], mnt[3]));
      m0 = fmaxf(m0, __shfl_xor(m0, 16));
      m0 = fmaxf(m0, __shfl_xor(m0, 32));
      float psum[4];
#pragma unroll
      for (int nt = 0; nt < 4; ++nt) {
#pragma unroll
        for (int r = 0; r < 4; ++r)
          sv[nt][r] = __builtin_amdgcn_exp2f(sv[nt][r] - m0);
        psum[nt] = (sv[nt][0] + sv[nt][1]) + (sv[nt][2] + sv[nt][3]);
      }
      float s0 = (psum[0] + psum[1]) + (psum[2] + psum[3]);
      s0 += __shfl_xor(s0, 16);
      s0 += __shfl_xor(s0, 32);
      const float rinv = 1.0f / s0;
#pragma unroll
      for (int nt = 0; nt < 4; ++nt) {
        ushort4 pk;
        pk.x = f2bf(sv[nt][0] * rinv);
        pk.y = f2bf(sv[nt][1] * rinv);
        pk.z = f2bf(sv[nt][2] * rinv);
        pk.w = f2bf(sv[nt][3] * rinv);
        *(ushort4*)(Sh + (mt * 16 + ln15) * 72 + nt * 16 + quad * 4) = pk;
      }
      // same-wave LDS RAW: wave-level drain, no block barrier needed
      asm volatile("s_waitcnt lgkmcnt(0)" ::: "memory");
      __builtin_amdgcn_sched_barrier(0);

      // PV swapped: mfma(V, P) -> D[m=chan][n=qtoken] -> ushort4 oa stores
      s16x8 pfr[2];
#pragma unroll
      for (int ks = 0; ks < 2; ++ks)
        pfr[ks] = *(const s16x8*)(Sh + (mt * 16 + ln15) * 72 + ks * 32 + quad * 8);
#pragma unroll
      for (int nt2 = 0; nt2 < 2; ++nt2) {
        f32x4 acc = {0.f, 0.f, 0.f, 0.f};
#pragma unroll
        for (int ks = 0; ks < 2; ++ks) {
          s16x8 vf = *(const s16x8*)(v_s + (h * 32 + nt2 * 16 + ln15) * 72 + ks * 32 + quad * 8);
          acc = mfma16(vf, pfr[ks], acc);       // swapped
        }
        *(ushort4*)(oa_s + (mt * 16 + ln15) * 136 + h * 32 + nt2 * 16 + m_sub) = pack4(acc);
      }
    }
    bar_lds();

    // ---- phase 5: out proj swapped -> float4 osr stores ------------------
    {
      const int nt  = wave >> 1;           // 0..7
      const int mtb = (wave & 1) * 2;      // {0,2}
      const unsigned short* wp = woutT + (nt * 16 + ln15) * 128 + quad * 8;
      s16x8 bfr[4];
#pragma unroll
      for (int ks = 0; ks < 4; ++ks) bfr[ks] = *(const s16x8*)(wp + ks * 32);
      float4 bo4 = *(const float4*)(b_out + nt * 16 + m_sub);
#pragma unroll
      for (int mi = 0; mi < 2; ++mi) {
        int mt = mtb + mi;
        f32x4 acc = {0.f, 0.f, 0.f, 0.f};
#pragma unroll
        for (int ks = 0; ks < 4; ++ks) {
          s16x8 af = *(const s16x8*)(oa_s + (mt * 16 + ln15) * 136 + ks * 32 + quad * 8);
          acc = mfma16(bfr[ks], af, acc);       // swapped: D[m=chan][n=token]
        }
        float4 o;
        o.x = acc[0] + bo4.x; o.y = acc[1] + bo4.y;
        o.z = acc[2] + bo4.z; o.w = acc[3] + bo4.w;
        *(float4*)(osr_s + (mt * 16 + ln15) * 132 + nt * 16 + m_sub) = o;
      }
    }
    bar_lds();

    // ---- phase 6: coalesced store -- full 512B token rows as float4 ------
    {
      float* outb = out + (long)b * BATCH_STRIDE;
      float4 o0 = *(const float4*)(osr_s + tokA * 132 + c4 * 4);
      *(float4*)(outb + offA) = o0;
      float4 o1 = *(const float4*)(osr_s + tokB * 132 + c4 * 4);
      *(float4*)(outb + offB) = o1;
    }
    // no barrier here: next ph1 touches xs/q/k/v (disjoint from osr); the
    // ph1-end barrier orders these ds_reads against next ph2's S writes.
  }
}

extern "C" void kernel_launch(void* const* d_in, const int* in_sizes, int n_in,
                              void* d_out, int out_size, void* d_ws, size_t ws_size,
                              hipStream_t stream) {
  const float* x    = (const float*)d_in[0];
  const float* wqkv = (const float*)d_in[1];
  const float* wout = (const float*)d_in[2];
  const float* bout = (const float*)d_in[3];
  const float* pe   = (const float*)d_in[4];
  const float* ulm  = (const float*)d_in[5];
  const float* lrm  = (const float*)d_in[6];

  unsigned short* wqkvT = (unsigned short*)d_ws;           // 384*128 bf16
  unsigned short* woutT = wqkvT + 384 * 128;               // 128*128 bf16

  prep_weights<<<(384 * 128 + 128 * 128) / 256, 256, 0, stream>>>(wqkv, wout, wqkvT, woutT);
  swin_fused<<<16 * 16, 1024, 0, stream>>>(x, wqkvT, woutT, bout, pe, ulm, lrm,
                                           (float*)d_out);
}

// Round 13
// 284.855 us; speedup vs baseline: 1.0093x; 1.0093x over previous
//
#include <hip/hip_runtime.h>

// Swin window attention, fully fused, persistent blocks (1 block/CU, 256
// blocks, 16-batch loop per block).
//
// R11 = R10 (126.6us) + ph1-weight-fragment hoisting.
// R10 post-mortem: LDS-issue cuts (hoisted A-frags, vectorized q/k/oa/osr
// stores) were a NULL result (126.4 -> 126.6) -- LDS issue is not the
// critical path. New census: ph1+ph5 re-load 16KB/wave of loop-invariant
// weight fragments from global EVERY iteration = 256KB/CU/iter; weights
// (128KB) >> L1 (32KB) so this is all L2 traffic (~1GB/dispatch, ~200cy
// latency right after barriers where nothing hides it). Fix: hoist the 12
// QKV weight fragments (48 VGPR) + bo4 out of the batch loop -- they are
// constant across b. VGPR budget: 64 + 48 + 4 ~= 116 <= 128 (the 16-wave/CU
// occupancy bound); ph5 weights (+16) and bias (+16) deferred to stay under.
// Tripwire: hbm_bytes > ~220MB means the compiler spilled -> revert.
// R4 note: weight-hoisting was tried at the 213us regime and measured null
// (masked by the then-dominant barrier drain); at 126us the L2 term is ~25%.
//
// MFMA 16x16x32 bf16 fragment layouts (HW-verified per guide m89/m91/m120):
//   A[m][k]: m = lane&15, k = (lane>>4)*8 + j   (8 contiguous bf16 = 16B)
//   B[k][n]: n = lane&15, k = (lane>>4)*8 + j
//   D[m][n]: n = lane&15, m = (lane>>4)*4 + reg
// Swapped forms used here: mfma(W-frag, X-frag) -> D[m=chan][n=token];
// mfma(K,Q) -> lane owns a full q-row of S (in-lane softmax, R9).

typedef __bf16 bf16x8 __attribute__((ext_vector_type(8)));
typedef short  s16x8  __attribute__((ext_vector_type(8)));
typedef float  f32x4  __attribute__((ext_vector_type(4)));

static __device__ __forceinline__ unsigned short f2bf(float f) {
  __bf16 h = (__bf16)f;                      // RNE; compiler emits cvt_pk pairs
  return __builtin_bit_cast(unsigned short, h);
}
static __device__ __forceinline__ ushort4 pack4(f32x4 a) {
  ushort4 pk;
  pk.x = f2bf(a[0]); pk.y = f2bf(a[1]); pk.z = f2bf(a[2]); pk.w = f2bf(a[3]);
  return pk;
}
static __device__ __forceinline__ f32x4 mfma16(s16x8 a, s16x8 b, f32x4 c) {
  return __builtin_amdgcn_mfma_f32_16x16x32_bf16(
      __builtin_bit_cast(bf16x8, a), __builtin_bit_cast(bf16x8, b), c, 0, 0, 0);
}
// LDS-only barrier: orders ds ops across waves without draining vmcnt.
static __device__ __forceinline__ void bar_lds() {
  __builtin_amdgcn_sched_barrier(0);
  asm volatile("s_waitcnt lgkmcnt(0)" ::: "memory");
  __builtin_amdgcn_s_barrier();
  __builtin_amdgcn_sched_barrier(0);
}

// ---------------- prep: transpose + bf16-cast weights into workspace --------
__global__ void prep_weights(const float* __restrict__ wqkv,
                             const float* __restrict__ wout,
                             unsigned short* __restrict__ wqkvT,
                             unsigned short* __restrict__ woutT) {
  int idx = blockIdx.x * blockDim.x + threadIdx.x;
  const int total1 = 384 * 128;
  if (idx < total1) {
    int n = idx >> 7, k = idx & 127;
    wqkvT[idx] = f2bf(wqkv[k * 384 + n]);
  } else {
    int i2 = idx - total1;
    int n = i2 >> 7, k = i2 & 127;
    woutT[i2] = f2bf(wout[k * 128 + n]);
  }
}

// ---------------- LDS layout ------------------------------------------------
//   xs   [64][136] bf16   17408  @ 0        (staged x window, batch-cycled)
//   q    [64][136] bf16   17408  @ 17408
//   k    [64][136] bf16   17408  @ 34816
//   v    [128][72] bf16   18432  @ 52224    (v transposed: [ch][tok])
//   S    [4][64][72] bf16 36864  @ 70656    (P in ph2; f32 osr[64][132] union)
//   oa   [64][136] bf16   17408  @ 107520
//   bias [64][68] f32     17408  @ 124928   (pre-scaled by log2e)
#define OFF_XS  0
#define OFF_Q   17408
#define OFF_K   34816
#define OFF_V   52224
#define OFF_S   70656
#define OFF_OA  107520
#define OFF_BI  124928
#define SMEM_SZ 142336

#define BATCH_STRIDE (128 * 128 * 128)   // floats per batch image

__global__ __launch_bounds__(1024, 4)
void swin_fused(const float* __restrict__ x,
                const unsigned short* __restrict__ wqkvT,
                const unsigned short* __restrict__ woutT,
                const float* __restrict__ b_out,
                const float* __restrict__ pe,     // [15][15]
                const float* __restrict__ ulm,    // [64][64]
                const float* __restrict__ lrm,    // [64][64]
                float* __restrict__ out) {
  __shared__ __align__(16) unsigned char smem[SMEM_SZ];
  unsigned short* xs_s   = (unsigned short*)(smem + OFF_XS);
  unsigned short* q_s    = (unsigned short*)(smem + OFF_Q);
  unsigned short* k_s    = (unsigned short*)(smem + OFF_K);
  unsigned short* v_s    = (unsigned short*)(smem + OFF_V);
  unsigned short* S_s    = (unsigned short*)(smem + OFF_S);
  float*          osr_s  = (float*)(smem + OFF_S);          // union with S
  unsigned short* oa_s   = (unsigned short*)(smem + OFF_OA);
  float*          bias_s = (float*)(smem + OFF_BI);

  const int tid  = threadIdx.x;
  const int lane = tid & 63;
  const int wave = tid >> 6;       // 0..15
  const int ln15 = lane & 15;
  const int quad = lane >> 4;
  const int m_sub = quad << 2;

  const int wh = blockIdx.x >> 4, ww = blockIdx.x & 15;

  // per-thread x/out addresses: 2 token-quarter-rows per thread, constant
  // across batches (only the batch base advances).
  const int tokA = tid >> 5, c4 = tid & 31;    // 32 float4 per 128-ch token row
  const int tokB = tokA + 32;
  const int giA = ((wh << 3) + (tokA >> 3) + 4) & 127;
  const int gjA = ((ww << 3) + (tokA & 7) + 4) & 127;
  const int giB = ((wh << 3) + (tokB >> 3) + 4) & 127;
  const int gjB = ((ww << 3) + (tokB & 7) + 4) & 127;
  const long offA = (long)(giA * 128 + gjA) * 128 + c4 * 4;
  const long offB = (long)(giB * 128 + gjB) * 128 + c4 * 4;
  const float* xA = x + offA;
  const float* xB = x + offB;

  // ph1 task constants: fixed mh = wave&1; col0 = (wave>>1)*16 for q/k/v.
  const int mh   = wave & 1;
  const int col0 = (wave >> 1) << 4;

  // ---- hoisted loop-invariant weight fragments (48 VGPR) + bo4 ----
  // The 12 QKV fragments are re-used every batch iteration; loading them
  // in-loop was 192KB/CU/iter of L2 traffic (the R10 null-result census).
  s16x8 wq[4], wk[4], wv[4];
  {
    const unsigned short* wpq = wqkvT + (col0 + ln15) * 128 + quad * 8;
    const unsigned short* wpk = wqkvT + (128 + col0 + ln15) * 128 + quad * 8;
    const unsigned short* wpv = wqkvT + (256 + col0 + ln15) * 128 + quad * 8;
#pragma unroll
    for (int ks = 0; ks < 4; ++ks) {
      wq[ks] = *(const s16x8*)(wpq + ks * 32);
      wk[ks] = *(const s16x8*)(wpk + ks * 32);
      wv[ks] = *(const s16x8*)(wpv + ks * 32);
    }
  }
  const int nt_p  = wave >> 1;           // ph5 constants
  const int mtb_p = (wave & 1) * 2;
  float4 bo4 = *(const float4*)(b_out + nt_p * 16 + m_sub);

  // ---- prologue: stage batch-0 x window + build bias table (once) ----
  {
    float4 a0 = *(const float4*)xA;
    float4 b0 = *(const float4*)xB;
    ushort4 pk;
    pk.x = f2bf(a0.x); pk.y = f2bf(a0.y); pk.z = f2bf(a0.z); pk.w = f2bf(a0.w);
    *(ushort4*)(xs_s + tokA * 136 + c4 * 4) = pk;
    pk.x = f2bf(b0.x); pk.y = f2bf(b0.y); pk.z = f2bf(b0.z); pk.w = f2bf(b0.w);
    *(ushort4*)(xs_s + tokB * 136 + c4 * 4) = pk;

    const bool has_ul = (wh == 15), has_lr = (ww == 15);
    const float log2e = 1.4426950408889634f;
#pragma unroll
    for (int it = 0; it < 4; ++it) {
      int t = tid + it * 1024;             // 4096 bias entries
      int i = t >> 6, j = t & 63;
      int r0 = (j >> 3) - (i >> 3) + 7;
      int r1 = (j & 7) - (i & 7) + 7;
      float bsum = pe[r0 * 15 + r1];
      if (has_ul) bsum += ulm[t];
      if (has_lr) bsum += lrm[t];
      bias_s[i * 68 + j] = bsum * log2e;   // log2 domain for exp2 softmax
    }
  }
  __syncthreads();

  for (int b = 0; b < 16; ++b) {
    // ---- phase 1: QKV GEMM + prefetch issue ------------------------------
    float4 pfA, pfB;
    const bool pf = (b < 15);
    if (pf) {
      pfA = *(const float4*)(xA + (b + 1) * BATCH_STRIDE);
      pfB = *(const float4*)(xB + (b + 1) * BATCH_STRIDE);
    }
    {
      // A-frags: this wave's 2 m-tiles x 4 k-slices, read ONCE per iter.
      s16x8 afr[2][4];
#pragma unroll
      for (int mi = 0; mi < 2; ++mi)
#pragma unroll
        for (int ks = 0; ks < 4; ++ks)
          afr[mi][ks] = *(const s16x8*)(xs_s + ((mh * 2 + mi) * 16 + ln15) * 136 + ks * 32 + quad * 8);

      // q task (swapped: D[m=chan][n=token] -> ushort4 store per mi)
#pragma unroll
      for (int mi = 0; mi < 2; ++mi) {
        f32x4 acc = {0.f, 0.f, 0.f, 0.f};
#pragma unroll
        for (int ks = 0; ks < 4; ++ks) acc = mfma16(wq[ks], afr[mi][ks], acc);
        *(ushort4*)(q_s + ((mh * 2 + mi) * 16 + ln15) * 136 + col0 + m_sub) = pack4(acc);
      }
      // k task (swapped)
#pragma unroll
      for (int mi = 0; mi < 2; ++mi) {
        f32x4 acc = {0.f, 0.f, 0.f, 0.f};
#pragma unroll
        for (int ks = 0; ks < 4; ++ks) acc = mfma16(wk[ks], afr[mi][ks], acc);
        *(ushort4*)(k_s + ((mh * 2 + mi) * 16 + ln15) * 136 + col0 + m_sub) = pack4(acc);
      }
      // v task (unswapped: D[m=tok][n=chan] -> ushort4 over tok, [ch][tok])
#pragma unroll
      for (int mi = 0; mi < 2; ++mi) {
        f32x4 acc = {0.f, 0.f, 0.f, 0.f};
#pragma unroll
        for (int ks = 0; ks < 4; ++ks) acc = mfma16(afr[mi][ks], wv[ks], acc);
        *(ushort4*)(v_s + (col0 + ln15) * 72 + (mh * 2 + mi) * 16 + m_sub) = pack4(acc);
      }
    }
    bar_lds();

    // ---- phase 2 (fused): swapped QK^T -> in-lane softmax -> P -> PV -----
    {
      const int h  = wave >> 2;
      const int mt = wave & 3;
      unsigned short* Sh = S_s + h * 64 * 72;
      s16x8 qf = *(const s16x8*)(q_s + (mt * 16 + ln15) * 136 + h * 32 + quad * 8);
      const float scale2 = 0.17677669529663687f * 1.4426950408889634f;
      const float* brow = bias_s + (mt * 16 + ln15) * 68;   // bias'[qt][*]
      f32x4 sv[4];
#pragma unroll
      for (int nt = 0; nt < 4; ++nt) {
        s16x8 kf = *(const s16x8*)(k_s + (nt * 16 + ln15) * 136 + h * 32 + quad * 8);
        f32x4 acc = {0.f, 0.f, 0.f, 0.f};
        acc = mfma16(kf, qf, acc);              // swapped: D[kt-local][qt-local]
        float4 bv = *(const float4*)(brow + nt * 16 + quad * 4);
#pragma unroll
        for (int r = 0; r < 4; ++r)
          sv[nt][r] = acc[r] * scale2 + ((const float*)&bv)[r];
      }

      // write next batch's prefetched x window (xs dead since ph1-end bar)
      if (pf) {
        ushort4 pk;
        pk.x = f2bf(pfA.x); pk.y = f2bf(pfA.y); pk.z = f2bf(pfA.z); pk.w = f2bf(pfA.w);
        *(ushort4*)(xs_s + tokA * 136 + c4 * 4) = pk;
        pk.x = f2bf(pfB.x); pk.y = f2bf(pfB.y); pk.z = f2bf(pfB.z); pk.w = f2bf(pfB.w);
        *(ushort4*)(xs_s + tokB * 136 + c4 * 4) = pk;
      }

      // in-lane softmax over the lane's full q-row + 2 cross-quad shfls.
      float mnt[4];
#pragma unroll
      for (int nt = 0; nt < 4; ++nt)
        mnt[nt] = fmaxf(fmaxf(sv[nt][0], sv[nt][1]), fmaxf(sv[nt][2], sv[nt][3]));
      float m0 = fmaxf(fmaxf(mnt[0], mnt[1]), fmaxf(mnt[2], mnt[3]));
      m0 = fmaxf(m0, __shfl_xor(m0, 16));
      m0 = fmaxf(m0, __shfl_xor(m0, 32));
      float psum[4];
#pragma unroll
      for (int nt = 0; nt < 4; ++nt) {
#pragma unroll
        for (int r = 0; r < 4; ++r)
          sv[nt][r] = __builtin_amdgcn_exp2f(sv[nt][r] - m0);
        psum[nt] = (sv[nt][0] + sv[nt][1]) + (sv[nt][2] + sv[nt][3]);
      }
      float s0 = (psum[0] + psum[1]) + (psum[2] + psum[3]);
      s0 += __shfl_xor(s0, 16);
      s0 += __shfl_xor(s0, 32);
      const float rinv = 1.0f / s0;
#pragma unroll
      for (int nt = 0; nt < 4; ++nt) {
        ushort4 pk;
        pk.x = f2bf(sv[nt][0] * rinv);
        pk.y = f2bf(sv[nt][1] * rinv);
        pk.z = f2bf(sv[nt][2] * rinv);
        pk.w = f2bf(sv[nt][3] * rinv);
        *(ushort4*)(Sh + (mt * 16 + ln15) * 72 + nt * 16 + quad * 4) = pk;
      }
      // same-wave LDS RAW: wave-level drain, no block barrier needed
      asm volatile("s_waitcnt lgkmcnt(0)" ::: "memory");
      __builtin_amdgcn_sched_barrier(0);

      // PV swapped: mfma(V, P) -> D[m=chan][n=qtoken] -> ushort4 oa stores
      s16x8 pfr[2];
#pragma unroll
      for (int ks = 0; ks < 2; ++ks)
        pfr[ks] = *(const s16x8*)(Sh + (mt * 16 + ln15) * 72 + ks * 32 + quad * 8);
#pragma unroll
      for (int nt2 = 0; nt2 < 2; ++nt2) {
        f32x4 acc = {0.f, 0.f, 0.f, 0.f};
#pragma unroll
        for (int ks = 0; ks < 2; ++ks) {
          s16x8 vf = *(const s16x8*)(v_s + (h * 32 + nt2 * 16 + ln15) * 72 + ks * 32 + quad * 8);
          acc = mfma16(vf, pfr[ks], acc);       // swapped
        }
        *(ushort4*)(oa_s + (mt * 16 + ln15) * 136 + h * 32 + nt2 * 16 + m_sub) = pack4(acc);
      }
    }
    bar_lds();

    // ---- phase 5: out proj swapped -> float4 osr stores ------------------
    {
      const unsigned short* wp = woutT + (nt_p * 16 + ln15) * 128 + quad * 8;
      s16x8 bfr[4];
#pragma unroll
      for (int ks = 0; ks < 4; ++ks) bfr[ks] = *(const s16x8*)(wp + ks * 32);
#pragma unroll
      for (int mi = 0; mi < 2; ++mi) {
        int mt = mtb_p + mi;
        f32x4 acc = {0.f, 0.f, 0.f, 0.f};
#pragma unroll
        for (int ks = 0; ks < 4; ++ks) {
          s16x8 af = *(const s16x8*)(oa_s + (mt * 16 + ln15) * 136 + ks * 32 + quad * 8);
          acc = mfma16(bfr[ks], af, acc);       // swapped: D[m=chan][n=token]
        }
        float4 o;
        o.x = acc[0] + bo4.x; o.y = acc[1] + bo4.y;
        o.z = acc[2] + bo4.z; o.w = acc[3] + bo4.w;
        *(float4*)(osr_s + (mt * 16 + ln15) * 132 + nt_p * 16 + m_sub) = o;
      }
    }
    bar_lds();

    // ---- phase 6: coalesced store -- full 512B token rows as float4 ------
    {
      float* outb = out + (long)b * BATCH_STRIDE;
      float4 o0 = *(const float4*)(osr_s + tokA * 132 + c4 * 4);
      *(float4*)(outb + offA) = o0;
      float4 o1 = *(const float4*)(osr_s + tokB * 132 + c4 * 4);
      *(float4*)(outb + offB) = o1;
    }
    // no barrier here: next ph1 touches xs/q/k/v (disjoint from osr); the
    // ph1-end barrier orders these ds_reads against next ph2's S writes.
  }
}

extern "C" void kernel_launch(void* const* d_in, const int* in_sizes, int n_in,
                              void* d_out, int out_size, void* d_ws, size_t ws_size,
                              hipStream_t stream) {
  const float* x    = (const float*)d_in[0];
  const float* wqkv = (const float*)d_in[1];
  const float* wout = (const float*)d_in[2];
  const float* bout = (const float*)d_in[3];
  const float* pe   = (const float*)d_in[4];
  const float* ulm  = (const float*)d_in[5];
  const float* lrm  = (const float*)d_in[6];

  unsigned short* wqkvT = (unsigned short*)d_ws;           // 384*128 bf16
  unsigned short* woutT = wqkvT + 384 * 128;               // 128*128 bf16

  prep_weights<<<(384 * 128 + 128 * 128) / 256, 256, 0, stream>>>(wqkv, wout, wqkvT, woutT);
  swin_fused<<<16 * 16, 1024, 0, stream>>>(x, wqkvT, woutT, bout, pe, ulm, lrm,
                                           (float*)d_out);
}